// Round 15
// baseline (108.992 us; speedup 1.0000x reference)
//
#include <hip/hip_runtime.h>

// Problem constants (fixed by setup_inputs): B=4, C=4, H=W=64, K=8192
#define BB 4
#define CC 4
#define NN 4096            // H*W
#define KK 8192
#define NPOS 16384         // B*N
#define SLICES 8
#define SLICE_K (KK / SLICES)   // 1024
#define ITERS (SLICE_K / 64)    // 16
#define POSW 8                  // positions per wave

// Output layout (float32 elements): [0..65535] dec_in; [65536] codebook_loss;
// [65537] commitment_loss; [65538..81921] closest_idx
#define OUT_LOSS 65536
#define OUT_IDX  65538

// ws layout (bytes):
//   [0, 1M)          u64 partial keys [NPOS][SLICES]
//   [1M, 1.5M)       qpre: 8192 position-pairs x 16 floats (interleaved q + qq)
//   [1.5M, +32K)     nrm: 8192 codebook norms
//   [then, +8)       { float lossAcc; unsigned cnt; }
#define KEYS_BYTES (NPOS * SLICES * 8)
#define QPRE_BYTE_OFF KEYS_BYTES
#define NRM_BYTE_OFF  (QPRE_BYTE_OFF + 8192 * 16 * 4)
#define ACC_BYTE_OFF  (NRM_BYTE_OFF + 8192 * 4)

struct LossAcc { float sum; unsigned int cnt; };

// Monotone float->uint map: preserves < ordering for all finite floats.
__device__ __forceinline__ unsigned int fkey(float s) {
    unsigned int u = __float_as_uint(s);
    return (u & 0x80000000u) ? ~u : (u | 0x80000000u);
}

// Force a wave-uniform float into an SGPR (frees VGPRs; VALU may read 1 SGPR).
__device__ __forceinline__ float uniform_f(float x) {
    return __int_as_float(__builtin_amdgcn_readfirstlane(__float_as_int(x)));
}

// Prequant + codebook norms (hoisted). Thread t: norm for k=t and prequant for
// position pair (2t, 2t+1), stored interleaved (layout consumed by vq_search).
__global__ __launch_bounds__(256) void vq_pre(const float* __restrict__ x,
                                              const float* __restrict__ pw,
                                              const float* __restrict__ pb,
                                              const float* __restrict__ cb,
                                              float* __restrict__ qpre,
                                              float* __restrict__ nrm,
                                              LossAcc* __restrict__ acc) {
    int t = blockIdx.x * 256 + threadIdx.x;   // grid 32*256 == 8192 exactly
    if (t == 0) { acc->sum = 0.0f; acc->cnt = 0u; }

    // codebook norm, numpy-style rounding (identical to reference sum(cb*cb))
    const float* e = cb + t * 4;
    float n0 = __fmul_rn(e[0], e[0]);
    n0 = __fadd_rn(n0, __fmul_rn(e[1], e[1]));
    n0 = __fadd_rn(n0, __fmul_rn(e[2], e[2]));
    n0 = __fadd_rn(n0, __fmul_rn(e[3], e[3]));
    nrm[t] = n0;

    // prequant for positions 2t, 2t+1 (same b; n even -> float2 aligned)
    int pos = 2 * t;
    int b = pos >> 12, n = pos & 4095;
    const float2* px = (const float2*)(x + b * (CC * NN) + n);
    float2 xv0 = px[0], xv1 = px[NN / 2], xv2 = px[NN], xv3 = px[3 * NN / 2];

    float qs[2][4], qqs[2];
#pragma unroll
    for (int h = 0; h < 2; ++h) {
        float a0 = h ? xv0.y : xv0.x, a1 = h ? xv1.y : xv1.x;
        float a2 = h ? xv2.y : xv2.x, a3 = h ? xv3.y : xv3.x;
#pragma unroll
        for (int o = 0; o < 4; ++o) {
            // einsum "bchw,oc->bohw": BLAS-style fma chain, ascending c
            float tt = fmaf(pw[o * 4 + 0], a0, 0.0f);
            tt = fmaf(pw[o * 4 + 1], a1, tt);
            tt = fmaf(pw[o * 4 + 2], a2, tt);
            tt = fmaf(pw[o * 4 + 3], a3, tt);
            qs[h][o] = __fadd_rn(tt, pb[o]);
        }
        // ||q||^2 numpy-style: rounded products, sequential adds
        float s = __fmul_rn(qs[h][0], qs[h][0]);
        s = __fadd_rn(s, __fmul_rn(qs[h][1], qs[h][1]));
        s = __fadd_rn(s, __fmul_rn(qs[h][2], qs[h][2]));
        s = __fadd_rn(s, __fmul_rn(qs[h][3], qs[h][3]));
        qqs[h] = s;
    }

    // interleaved layout: [qA0,qB0,qA1,qB1][qA2,qB2,qA3,qB3][qqA,qqB,...]
    float4* o4 = (float4*)(qpre + t * 16);
    o4[0] = make_float4(qs[0][0], qs[1][0], qs[0][1], qs[1][1]);
    o4[1] = make_float4(qs[0][2], qs[1][2], qs[0][3], qs[1][3]);
    ((float2*)(qpre + t * 16 + 8))[0] = make_float2(qqs[0], qqs[1]);
}

// Round-14 lesson: with global per-iter loads, ~8 resident blocks/CU spanned 4
// K-slices -> 160KB working set through 32KB L1 -> load-path bound at ~40us
// regardless of inner-loop codegen. Fix: stage the slice in LDS (20KB: 16KB cb
// + 4KB norms), overlay the 16KB keys buffer on the staged cb after the loop.
// 20KB/block -> 8 blocks/CU -> 32 waves/CU. Round-5 lesson: NO min-waves bound.
__global__ __launch_bounds__(256) void vq_search(const float* __restrict__ cb,
                                                 const float* __restrict__ qpre,
                                                 const float* __restrict__ nrm,
                                                 unsigned long long* __restrict__ keys_ws) {
    __shared__ __align__(16) char smem[20480];   // 16KB cb stage | 4KB norms
    float4* lcb = (float4*)smem;
    float*  lnr = (float*)(smem + 16384);

    const int tid   = threadIdx.x;
    const int lane  = tid & 63;
    const int wave  = tid >> 6;
    const int slice = blockIdx.x & (SLICES - 1);
    const int pg    = blockIdx.x >> 3;             // 0..511 position-group
    const int k0    = slice * SLICE_K;

    // ---- stage slice: 1024 float4 cb + 256 float4 of norms (coalesced) ----
    {
        const float4* gcb = (const float4*)cb + k0;
#pragma unroll
        for (int i = 0; i < 4; ++i) lcb[tid + 256 * i] = gcb[tid + 256 * i];
        ((float4*)lnr)[tid] = ((const float4*)(nrm + k0))[tid];
    }

    // q/qq for this wave's 8 positions -> SGPRs (wave-uniform loads).
    // qpre layout: pair g holds positions 2g (h=0), 2g+1 (h=1).
    float q[POSW][4], qq[POSW];
    {
        const float* qp = qpre + ((pg * 4 + wave) * 4) * 16;
#pragma unroll
        for (int p = 0; p < POSW; ++p) {
            int g = p >> 1, h = p & 1;
#pragma unroll
            for (int c = 0; c < 4; ++c)
                q[p][c] = uniform_f(qp[g * 16 + c * 2 + h]);
            qq[p] = uniform_f(qp[g * 16 + 8 + h]);
        }
    }
    __syncthreads();   // staging visible to all waves

    float best[POSW];
    int   bit_[POSW];   // winning ITERATION id (4 bits); k reconstructed at end
#pragma unroll
    for (int p = 0; p < POSW; ++p) { best[p] = __int_as_float(0x7f800000); bit_[p] = 0; }

#pragma unroll 2
    for (int it = 0; it < ITERS; ++it) {
        float4 e  = lcb[it * 64 + lane];   // ds_read_b128, conflict-free
        float  nk = lnr[it * 64 + lane];   // ds_read_b32, conflict-free
#pragma unroll
        for (int p = 0; p < POSW; ++p) {
            // dot chain == the passing kernel's fmaf sequence (q in SGPR, e in VGPR)
            float d = fmaf(q[p][0], e.x, 0.0f);
            d = fmaf(q[p][1], e.y, d);
            d = fmaf(q[p][2], e.z, d);
            d = fmaf(q[p][3], e.w, d);
            // (qq - 2*dot) + nk ; -2.0 inline const, qq is the 1 SGPR source
            float s = __fadd_rn(fmaf(-2.0f, d, qq[p]), nk);
            if (s < best[p]) { best[p] = s; bit_[p] = it; }  // strict <: first k wins
        }
    }
    __syncthreads();   // all reads of the stage done -> safe to overlay keys

    // overlay packed (fkey(dist), k) keys on the staged-cb LDS region (16KB)
    unsigned long long (*keys)[POSW][64] = (unsigned long long (*)[POSW][64])smem;
#pragma unroll
    for (int p = 0; p < POSW; ++p) {
        int kfull = k0 + lane + (bit_[p] << 6);
        keys[wave][p][lane] =
            ((unsigned long long)fkey(best[p]) << 32) | (unsigned int)kfull;
    }
    __syncthreads();

    // one thread per (wave,pos): reduce 64 keys (proven pattern)
    if (tid < 32) {
        int w = tid >> 3, p = tid & 7;
        unsigned long long bk = ~0ull;
#pragma unroll 4
        for (int i = 0; i < 64; ++i) {
            unsigned long long c = keys[w][p][i ^ tid];    // XOR spreads LDS banks
            bk = (c < bk) ? c : bk;
        }
        int pos = (pg * 4 + w) * 8 + p;
        keys_ws[pos * SLICES + slice] = bk;
    }
}

// Epilogue + loss finalization fused (last-block pattern).
__global__ __launch_bounds__(256) void vq_epi(const float* __restrict__ x,
                                              const float* __restrict__ cb,
                                              const float* __restrict__ qw,
                                              const float* __restrict__ qb,
                                              const unsigned long long* __restrict__ keys_ws,
                                              LossAcc* __restrict__ acc,
                                              float* __restrict__ out) {
    __shared__ float red[256];
    const int tid = threadIdx.x;
    const int pos = blockIdx.x * 256 + tid;   // 64 blocks x 256 = NPOS

    // combine the 8 slice winners (min key = global first-occurrence argmin)
    unsigned long long bk = keys_ws[pos * SLICES + 0];
#pragma unroll
    for (int j = 1; j < SLICES; ++j) {
        unsigned long long c = keys_ws[pos * SLICES + j];
        bk = (c < bk) ? c : bk;
    }
    int idx = (int)(bk & 0xFFFFFFFFull);

    int b = pos >> 12, n = pos & 4095;
    const float4* cb4 = (const float4*)cb;
    float4 e = cb4[idx];

    const float* xb = x + b * (CC * NN) + n;
    float xv0 = xb[0], xv1 = xb[NN], xv2 = xb[2 * NN], xv3 = xb[3 * NN];

    // straight-through (forward): st = x + (quant - x), matching reference fp ops
    float s0 = __fadd_rn(xv0, __fsub_rn(e.x, xv0));
    float s1 = __fadd_rn(xv1, __fsub_rn(e.y, xv1));
    float s2 = __fadd_rn(xv2, __fsub_rn(e.z, xv2));
    float s3 = __fadd_rn(xv3, __fsub_rn(e.w, xv3));

    // postquant 1x1 conv -> float32 output (coalesced per-o: consecutive n)
#pragma unroll
    for (int o = 0; o < 4; ++o) {
        float t = fmaf(qw[o * 4 + 0], s0, 0.0f);
        t = fmaf(qw[o * 4 + 1], s1, t);
        t = fmaf(qw[o * 4 + 2], s2, t);
        t = fmaf(qw[o * 4 + 3], s3, t);
        t = __fadd_rn(t, qb[o]);
        out[b * (CC * NN) + o * NN + n] = t;
    }

    // index output as float32
    out[OUT_IDX + b * NN + n] = (float)idx;

    // loss partial: sum_c (quant - x)^2 (both losses identical in forward)
    float d0 = __fsub_rn(e.x, xv0), d1 = __fsub_rn(e.y, xv1);
    float d2 = __fsub_rn(e.z, xv2), d3 = __fsub_rn(e.w, xv3);
    float lp = __fmul_rn(d0, d0);
    lp = __fadd_rn(lp, __fmul_rn(d1, d1));
    lp = __fadd_rn(lp, __fmul_rn(d2, d2));
    lp = __fadd_rn(lp, __fmul_rn(d3, d3));

    red[tid] = lp;
    __syncthreads();
#pragma unroll
    for (int s = 128; s > 0; s >>= 1) {
        if (tid < s) red[tid] += red[tid + s];
        __syncthreads();
    }
    if (tid == 0) {
        atomicAdd(&acc->sum, red[0]);
        __threadfence();
        unsigned int old = atomicAdd(&acc->cnt, 1u);
        if (old == 63u) {   // last block: all 64 sums are fence-ordered before us
            float s = atomicAdd(&acc->sum, 0.0f);   // device-scope coherent read
            s *= (1.0f / (float)(NPOS * CC));
            out[OUT_LOSS + 0] = s;
            out[OUT_LOSS + 1] = s;
        }
    }
}

extern "C" void kernel_launch(void* const* d_in, const int* in_sizes, int n_in,
                              void* d_out, int out_size, void* d_ws, size_t ws_size,
                              hipStream_t stream) {
    const float* x  = (const float*)d_in[0];
    const float* pw = (const float*)d_in[1];
    const float* pb = (const float*)d_in[2];
    const float* cb = (const float*)d_in[3];
    const float* qw = (const float*)d_in[4];
    const float* qb = (const float*)d_in[5];
    float* out = (float*)d_out;

    unsigned long long* keys_ws = (unsigned long long*)d_ws;
    float* qpre  = (float*)((char*)d_ws + QPRE_BYTE_OFF);
    float* nrm   = (float*)((char*)d_ws + NRM_BYTE_OFF);
    LossAcc* acc = (LossAcc*)((char*)d_ws + ACC_BYTE_OFF);

    vq_pre<<<32, 256, 0, stream>>>(x, pw, pb, cb, qpre, nrm, acc);
    // grid: (NPOS/32 positions-per-block) * SLICES = 512*8 = 4096 blocks
    vq_search<<<(NPOS / 32) * SLICES, 256, 0, stream>>>(cb, qpre, nrm, keys_ws);
    vq_epi<<<NPOS / 256, 256, 0, stream>>>(x, cb, qw, qb, keys_ws, acc, out);
}

// Round 16
// 97.114 us; speedup vs baseline: 1.1223x; 1.1223x over previous
//
#include <hip/hip_runtime.h>

// Problem constants (fixed by setup_inputs): B=4, C=4, H=W=64, K=8192
#define BB 4
#define CC 4
#define NN 4096            // H*W
#define KK 8192
#define NPOS 16384         // B*N
#define SLICES 4
#define SLICE_K (KK / SLICES)   // 2048
#define ITERS (SLICE_K / 64)    // 32
#define POSW 16                 // positions per wave

// Output layout (float32 elements): [0..65535] dec_in; [65536] codebook_loss;
// [65537] commitment_loss; [65538..81921] closest_idx
#define OUT_LOSS 65536
#define OUT_IDX  65538

// ws layout (bytes):
//   [0, 512K)        u64 partial keys [NPOS][SLICES]
//   [512K, 1M)       qpre: 8192 position-pairs x 16 floats (interleaved q + qq)
//   [1M, 1M+32K)     nrm: 8192 codebook norms
//   [then, +8)       { float lossAcc; unsigned cnt; }
#define KEYS_BYTES (NPOS * SLICES * 8)
#define QPRE_BYTE_OFF KEYS_BYTES
#define NRM_BYTE_OFF  (QPRE_BYTE_OFF + 8192 * 16 * 4)
#define ACC_BYTE_OFF  (NRM_BYTE_OFF + 8192 * 4)

typedef float v2f __attribute__((ext_vector_type(2)));

struct LossAcc { float sum; unsigned int cnt; };

// Monotone float->uint map: preserves < ordering for all finite floats.
__device__ __forceinline__ unsigned int fkey(float s) {
    unsigned int u = __float_as_uint(s);
    return (u & 0x80000000u) ? ~u : (u | 0x80000000u);
}

__device__ __forceinline__ unsigned long long shflx_u64(unsigned long long v, int m) {
    unsigned int lo = __shfl_xor((unsigned int)v, m, 64);
    unsigned int hi = __shfl_xor((unsigned int)(v >> 32), m, 64);
    return ((unsigned long long)hi << 32) | lo;
}

// Prequant + codebook norms (hoisted). Thread t: norm for k=t and prequant for
// position pair (2t, 2t+1), stored interleaved for vq_search.
__global__ __launch_bounds__(256) void vq_pre(const float* __restrict__ x,
                                              const float* __restrict__ pw,
                                              const float* __restrict__ pb,
                                              const float* __restrict__ cb,
                                              float* __restrict__ qpre,
                                              float* __restrict__ nrm,
                                              LossAcc* __restrict__ acc) {
    int t = blockIdx.x * 256 + threadIdx.x;   // grid 32*256 == 8192 exactly
    if (t == 0) { acc->sum = 0.0f; acc->cnt = 0u; }

    // codebook norm, numpy-style rounding (identical to reference sum(cb*cb))
    const float* e = cb + t * 4;
    float n0 = __fmul_rn(e[0], e[0]);
    n0 = __fadd_rn(n0, __fmul_rn(e[1], e[1]));
    n0 = __fadd_rn(n0, __fmul_rn(e[2], e[2]));
    n0 = __fadd_rn(n0, __fmul_rn(e[3], e[3]));
    nrm[t] = n0;

    // prequant for positions 2t, 2t+1 (same b; n even -> float2 aligned)
    int pos = 2 * t;
    int b = pos >> 12, n = pos & 4095;
    const float2* px = (const float2*)(x + b * (CC * NN) + n);
    float2 xv0 = px[0], xv1 = px[NN / 2], xv2 = px[NN], xv3 = px[3 * NN / 2];

    float qs[2][4], qqs[2];
#pragma unroll
    for (int h = 0; h < 2; ++h) {
        float a0 = h ? xv0.y : xv0.x, a1 = h ? xv1.y : xv1.x;
        float a2 = h ? xv2.y : xv2.x, a3 = h ? xv3.y : xv3.x;
#pragma unroll
        for (int o = 0; o < 4; ++o) {
            // einsum "bchw,oc->bohw": BLAS-style fma chain, ascending c
            float tt = fmaf(pw[o * 4 + 0], a0, 0.0f);
            tt = fmaf(pw[o * 4 + 1], a1, tt);
            tt = fmaf(pw[o * 4 + 2], a2, tt);
            tt = fmaf(pw[o * 4 + 3], a3, tt);
            qs[h][o] = __fadd_rn(tt, pb[o]);
        }
        // ||q||^2 numpy-style: rounded products, sequential adds
        float s = __fmul_rn(qs[h][0], qs[h][0]);
        s = __fadd_rn(s, __fmul_rn(qs[h][1], qs[h][1]));
        s = __fadd_rn(s, __fmul_rn(qs[h][2], qs[h][2]));
        s = __fadd_rn(s, __fmul_rn(qs[h][3], qs[h][3]));
        qqs[h] = s;
    }

    // interleaved layout: [qA0,qB0,qA1,qB1][qA2,qB2,qA3,qB3][qqA,qqB,...]
    float4* o4 = (float4*)(qpre + t * 16);
    o4[0] = make_float4(qs[0][0], qs[1][0], qs[0][1], qs[1][1]);
    o4[1] = make_float4(qs[0][2], qs[1][2], qs[0][3], qs[1][3]);
    ((float2*)(qpre + t * 16 + 8))[0] = make_float2(qqs[0], qqs[1]);
}

// Session-best measured config (round 10: 97.49us total): 1-wave blocks,
// wave owns 16 positions x one 2048-entry K-slice, grid 4096.
// Round-5 lesson: NO min-waves launch bound (forced-VGPR spill disaster).
__global__ __launch_bounds__(64) void vq_search(const float* __restrict__ cb,
                                                const float* __restrict__ qpre,
                                                const float* __restrict__ nrm,
                                                unsigned long long* __restrict__ keys_ws) {
    __shared__ unsigned long long keys[POSW][64];  // 8 KB

    const int lane  = threadIdx.x;
    const int gid   = blockIdx.x;
    const int slice = gid & (SLICES - 1);
    const int pg    = gid >> 2;              // 0..1023; positions pg*16..+15
    const int k0    = slice * SLICE_K;

    // load 8 pre-interleaved q pairs (wave-uniform -> L1 broadcast)
    v2f q2[8][4], qq2[8];
    const float* qp = qpre + (pg * 8) * 16;
#pragma unroll
    for (int g = 0; g < 8; ++g) {
        float4 a = ((const float4*)(qp + g * 16))[0];
        float4 b = ((const float4*)(qp + g * 16))[1];
        float2 c = ((const float2*)(qp + g * 16 + 8))[0];
        q2[g][0] = (v2f){a.x, a.y};
        q2[g][1] = (v2f){a.z, a.w};
        q2[g][2] = (v2f){b.x, b.y};
        q2[g][3] = (v2f){b.z, b.w};
        qq2[g]   = (v2f){c.x, c.y};
    }

    float best[POSW];
    int   bit_[POSW];   // winning ITERATION id (5 bits); k reconstructed at end
#pragma unroll
    for (int p = 0; p < POSW; ++p) { best[p] = __int_as_float(0x7f800000); bit_[p] = 0; }

    const float4* cb4 = (const float4*)cb + k0 + lane;
    const float*  nr  = nrm + k0 + lane;

#pragma unroll 2
    for (int it = 0; it < ITERS; ++it) {
        float4 e  = cb4[it * 64];
        float  nk = nr[it * 64];
        v2f nk2 = (v2f){nk, nk};
        v2f ex = (v2f){e.x, e.x}, ey = (v2f){e.y, e.y};
        v2f ez = (v2f){e.z, e.z}, ew = (v2f){e.w, e.w};
#pragma unroll
        for (int g = 0; g < 8; ++g) {
            // dot chain: per-component == the passing kernel's fmaf sequence
            v2f d = q2[g][0] * ex;
            d = __builtin_elementwise_fma(q2[g][1], ey, d);
            d = __builtin_elementwise_fma(q2[g][2], ez, d);
            d = __builtin_elementwise_fma(q2[g][3], ew, d);
            v2f s = __builtin_elementwise_fma((v2f){-2.0f, -2.0f}, d, qq2[g]);
            s = s + nk2;   // pk add: per-component rounding == scalar __fadd_rn
            if (s.x < best[2 * g])     { best[2 * g]     = s.x; bit_[2 * g]     = it; }
            if (s.y < best[2 * g + 1]) { best[2 * g + 1] = s.y; bit_[2 * g + 1] = it; }
        }
    }

    // publish per-lane winners as packed (fkey(dist), k) keys
#pragma unroll
    for (int p = 0; p < POSW; ++p) {
        int kfull = k0 + lane + (bit_[p] << 6);
        keys[p][lane] = ((unsigned long long)fkey(best[p]) << 32) | (unsigned int)kfull;
    }
    __syncthreads();   // 1-wave block: cheap

    // 4 lanes per position: each scans 16 keys, then 2-step shfl_xor min
    int p  = lane >> 2;
    int j0 = (lane & 3) << 4;
    unsigned long long bk = keys[p][j0];
#pragma unroll
    for (int j = 1; j < 16; ++j) {
        unsigned long long c = keys[p][j0 + j];
        bk = (c < bk) ? c : bk;
    }
#pragma unroll
    for (int m = 1; m < 4; m <<= 1) {
        unsigned long long c = shflx_u64(bk, m);
        bk = (c < bk) ? c : bk;
    }
    if ((lane & 3) == 0)
        keys_ws[(pg * POSW + p) * SLICES + slice] = bk;
}

// Epilogue + loss finalization fused (last-block pattern).
__global__ __launch_bounds__(256) void vq_epi(const float* __restrict__ x,
                                              const float* __restrict__ cb,
                                              const float* __restrict__ qw,
                                              const float* __restrict__ qb,
                                              const unsigned long long* __restrict__ keys_ws,
                                              LossAcc* __restrict__ acc,
                                              float* __restrict__ out) {
    __shared__ float red[256];
    const int tid = threadIdx.x;
    const int pos = blockIdx.x * 256 + tid;   // 64 blocks x 256 = NPOS

    // combine the 4 slice winners (min key = global first-occurrence argmin)
    unsigned long long bk = keys_ws[pos * SLICES + 0];
#pragma unroll
    for (int j = 1; j < SLICES; ++j) {
        unsigned long long c = keys_ws[pos * SLICES + j];
        bk = (c < bk) ? c : bk;
    }
    int idx = (int)(bk & 0xFFFFFFFFull);

    int b = pos >> 12, n = pos & 4095;
    const float4* cb4 = (const float4*)cb;
    float4 e = cb4[idx];

    const float* xb = x + b * (CC * NN) + n;
    float xv0 = xb[0], xv1 = xb[NN], xv2 = xb[2 * NN], xv3 = xb[3 * NN];

    // straight-through (forward): st = x + (quant - x), matching reference fp ops
    float s0 = __fadd_rn(xv0, __fsub_rn(e.x, xv0));
    float s1 = __fadd_rn(xv1, __fsub_rn(e.y, xv1));
    float s2 = __fadd_rn(xv2, __fsub_rn(e.z, xv2));
    float s3 = __fadd_rn(xv3, __fsub_rn(e.w, xv3));

    // postquant 1x1 conv -> float32 output (coalesced per-o: consecutive n)
#pragma unroll
    for (int o = 0; o < 4; ++o) {
        float t = fmaf(qw[o * 4 + 0], s0, 0.0f);
        t = fmaf(qw[o * 4 + 1], s1, t);
        t = fmaf(qw[o * 4 + 2], s2, t);
        t = fmaf(qw[o * 4 + 3], s3, t);
        t = __fadd_rn(t, qb[o]);
        out[b * (CC * NN) + o * NN + n] = t;
    }

    // index output as float32
    out[OUT_IDX + b * NN + n] = (float)idx;

    // loss partial: sum_c (quant - x)^2 (both losses identical in forward)
    float d0 = __fsub_rn(e.x, xv0), d1 = __fsub_rn(e.y, xv1);
    float d2 = __fsub_rn(e.z, xv2), d3 = __fsub_rn(e.w, xv3);
    float lp = __fmul_rn(d0, d0);
    lp = __fadd_rn(lp, __fmul_rn(d1, d1));
    lp = __fadd_rn(lp, __fmul_rn(d2, d2));
    lp = __fadd_rn(lp, __fmul_rn(d3, d3));

    red[tid] = lp;
    __syncthreads();
#pragma unroll
    for (int s = 128; s > 0; s >>= 1) {
        if (tid < s) red[tid] += red[tid + s];
        __syncthreads();
    }
    if (tid == 0) {
        atomicAdd(&acc->sum, red[0]);
        __threadfence();
        unsigned int old = atomicAdd(&acc->cnt, 1u);
        if (old == 63u) {   // last block: all 64 sums are fence-ordered before us
            float s = atomicAdd(&acc->sum, 0.0f);   // device-scope coherent read
            s *= (1.0f / (float)(NPOS * CC));
            out[OUT_LOSS + 0] = s;
            out[OUT_LOSS + 1] = s;
        }
    }
}

extern "C" void kernel_launch(void* const* d_in, const int* in_sizes, int n_in,
                              void* d_out, int out_size, void* d_ws, size_t ws_size,
                              hipStream_t stream) {
    const float* x  = (const float*)d_in[0];
    const float* pw = (const float*)d_in[1];
    const float* pb = (const float*)d_in[2];
    const float* cb = (const float*)d_in[3];
    const float* qw = (const float*)d_in[4];
    const float* qb = (const float*)d_in[5];
    float* out = (float*)d_out;

    unsigned long long* keys_ws = (unsigned long long*)d_ws;
    float* qpre  = (float*)((char*)d_ws + QPRE_BYTE_OFF);
    float* nrm   = (float*)((char*)d_ws + NRM_BYTE_OFF);
    LossAcc* acc = (LossAcc*)((char*)d_ws + ACC_BYTE_OFF);

    vq_pre<<<32, 256, 0, stream>>>(x, pw, pb, cb, qpre, nrm, acc);
    vq_search<<<(NPOS / POSW) * SLICES, 64, 0, stream>>>(cb, qpre, nrm, keys_ws);
    vq_epi<<<NPOS / 256, 256, 0, stream>>>(x, cb, qw, qb, keys_ws, acc, out);
}